// Round 1
// baseline (398.422 us; speedup 1.0000x reference)
//
#include <hip/hip_runtime.h>
#include <type_traits>

typedef unsigned short u16;
typedef __attribute__((ext_vector_type(8))) short short8;   // 8 bf16 (4 VGPRs) MFMA frag
typedef __attribute__((ext_vector_type(4))) float floatx4;  // MFMA acc

#define DEV __device__ __forceinline__

DEV float bf2f(u16 u) { return __uint_as_float(((unsigned)u) << 16); }
DEV u16 f2bf(float f) {                       // RNE fp32->bf16
  unsigned u = __float_as_uint(f);
  u += 0x7fffu + ((u >> 16) & 1u);
  return (u16)(u >> 16);
}
DEV void unpack8(uint4 v, float* f) {
  f[0] = __uint_as_float(v.x << 16); f[1] = __uint_as_float(v.x & 0xffff0000u);
  f[2] = __uint_as_float(v.y << 16); f[3] = __uint_as_float(v.y & 0xffff0000u);
  f[4] = __uint_as_float(v.z << 16); f[5] = __uint_as_float(v.z & 0xffff0000u);
  f[6] = __uint_as_float(v.w << 16); f[7] = __uint_as_float(v.w & 0xffff0000u);
}
DEV void async16(const void* g, void* lds) {  // 16B global->LDS DMA (lane*16 implicit)
  __builtin_amdgcn_global_load_lds((const __attribute__((address_space(1))) void*)g,
                                   (__attribute__((address_space(3))) void*)lds, 16, 0, 0);
}

// ---------------- elementwise converts ----------------
__global__ __launch_bounds__(256) void k_cvt_x(const float* __restrict__ X, u16* __restrict__ Xb) {
  size_t i = ((size_t)blockIdx.x * 256 + threadIdx.x) * 8;
  float4 a = *(const float4*)(X + i);
  float4 b = *(const float4*)(X + i + 4);
  union { u16 s[8]; uint4 v; } o;
  o.s[0]=f2bf(a.x); o.s[1]=f2bf(a.y); o.s[2]=f2bf(a.z); o.s[3]=f2bf(a.w);
  o.s[4]=f2bf(b.x); o.s[5]=f2bf(b.y); o.s[6]=f2bf(b.z); o.s[7]=f2bf(b.w);
  *(uint4*)(Xb + i) = o.v;
}

// transpose-convert 1024x1024 fp32 (KxN) -> bf16 (NxK); z selects matrix
__global__ __launch_bounds__(256) void k_wt(const float* __restrict__ Wq, const float* __restrict__ Wk,
                                            const float* __restrict__ Wv, const float* __restrict__ Wo,
                                            u16* __restrict__ Wqkvt, u16* __restrict__ Wot) {
  const float* src; u16* dst;
  switch (blockIdx.z) {
    case 0:  src = Wq; dst = Wqkvt;            break;
    case 1:  src = Wk; dst = Wqkvt + 1048576;  break;
    case 2:  src = Wv; dst = Wqkvt + 2097152;  break;
    default: src = Wo; dst = Wot;              break;
  }
  __shared__ float tile[32][33];
  int tx = threadIdx.x & 31, ty = threadIdx.x >> 5;  // 32 x 8
  int n0 = blockIdx.x * 32, k0 = blockIdx.y * 32;
  #pragma unroll
  for (int i = 0; i < 32; i += 8) tile[ty + i][tx] = src[(size_t)(k0 + ty + i) * 1024 + n0 + tx];
  __syncthreads();
  #pragma unroll
  for (int i = 0; i < 32; i += 8) dst[(size_t)(n0 + ty + i) * 1024 + k0 + tx] = f2bf(tile[tx][ty + i]);
}

// ---------------- bf16 MFMA GEMM: C[M,N] = A[M,K] * Bt[N,K]^T + bias ----------------
// m97 structure: 128x128 tile, BK=32, 4 waves each 64x64 (4x4 MFMA 16x16x32), global_load_lds w=16
template <typename OutT>
__global__ __launch_bounds__(256)
void k_gemm_bt(const u16* __restrict__ A, const u16* __restrict__ B,
               const float* __restrict__ bias, OutT* __restrict__ C,
               int M, int N, int K) {
  __shared__ __align__(16) u16 As[128 * 32];
  __shared__ __align__(16) u16 Bs[128 * 32];
  const int t = threadIdx.x;
  const int w = t >> 6, lane = t & 63;
  const int m0 = blockIdx.y << 7, n0 = blockIdx.x << 7;
  const int wr = (w >> 1) << 6, wc = (w & 1) << 6;

  floatx4 acc[4][4];
  #pragma unroll
  for (int i = 0; i < 4; ++i)
    #pragma unroll
    for (int j = 0; j < 4; ++j)
      #pragma unroll
      for (int k = 0; k < 4; ++k) acc[i][j][k] = 0.f;

  const int rowA0 = t >> 2, koff = (t & 3) << 3;      // round 0: idx = t
  const int rowA1 = (256 + t) >> 2;                   // round 1: idx = 256+t (same koff)
  const int lr = lane & 15, lko = (lane >> 4) << 3;

  for (int kt = 0; kt < K; kt += 32) {
    __syncthreads();
    async16(A + (size_t)(m0 + rowA0) * K + kt + koff, &As[(w << 6) * 8]);
    async16(B + (size_t)(n0 + rowA0) * K + kt + koff, &Bs[(w << 6) * 8]);
    async16(A + (size_t)(m0 + rowA1) * K + kt + koff, &As[(256 + (w << 6)) * 8]);
    async16(B + (size_t)(n0 + rowA1) * K + kt + koff, &Bs[(256 + (w << 6)) * 8]);
    __syncthreads();
    short8 af[4], bfr[4];
    #pragma unroll
    for (int i = 0; i < 4; ++i) af[i]  = *(const short8*)&As[(wr + (i << 4) + lr) * 32 + lko];
    #pragma unroll
    for (int j = 0; j < 4; ++j) bfr[j] = *(const short8*)&Bs[(wc + (j << 4) + lr) * 32 + lko];
    #pragma unroll
    for (int i = 0; i < 4; ++i)
      #pragma unroll
      for (int j = 0; j < 4; ++j)
        acc[i][j] = __builtin_amdgcn_mfma_f32_16x16x32_bf16(af[i], bfr[j], acc[i][j], 0, 0, 0);
  }
  // C/D layout: col = lane&15, row = (lane>>4)*4 + reg
  const int lq = (lane >> 4) << 2;
  #pragma unroll
  for (int j = 0; j < 4; ++j) {
    const int cn = n0 + wc + (j << 4) + lr;
    const float bv = bias[cn];
    #pragma unroll
    for (int i = 0; i < 4; ++i) {
      const int rm = m0 + wr + (i << 4) + lq;
      #pragma unroll
      for (int rr = 0; rr < 4; ++rr) {
        float v = acc[i][j][rr] + bv;
        if constexpr (std::is_same<OutT, u16>::value) C[(size_t)(rm + rr) * N + cn] = f2bf(v);
        else                                          C[(size_t)(rm + rr) * N + cn] = v;
      }
    }
  }
}

// ---------------- Gram partials: Gpart[nh][chunk] = sum over 256 a of q_x q_y ----------------
__global__ __launch_bounds__(256)
void k_gpart(const u16* __restrict__ QKV, float* __restrict__ Gpart) {
  const int chunk = blockIdx.x;            // 0..7  (256 a each)
  const int nh = blockIdx.y;               // 0..63
  const int n = nh >> 4, h = nh & 15;
  const int t = threadIdx.x;
  __shared__ __align__(16) float lds[128 * 68];
  const u16* Qb = QKV + (size_t)(n * 2048 + h * 128 + chunk * 16) * 3072;  // Q at col offset 0
  float acc[4][4];
  #pragma unroll
  for (int i = 0; i < 4; ++i)
    #pragma unroll
    for (int j = 0; j < 4; ++j) acc[i][j] = 0.f;
  const int tx = t & 15, ty = t >> 4;
  for (int s = 0; s < 2; ++s) {            // two 128-a stages (8 Q rows each)
    __syncthreads();
    #pragma unroll
    for (int i = 0; i < 4; ++i) {
      int f = ((i << 8) + t) << 3;         // 0..8191
      int row = f >> 10, j = f & 1023;
      uint4 v = *(const uint4*)(Qb + (size_t)((s << 3) + row) * 3072 + j);
      float tmp[8]; unpack8(v, tmp);
      float* d = &lds[((row << 4) + (j >> 6)) * 68 + (j & 63)];
      #pragma unroll
      for (int k = 0; k < 8; ++k) d[k] = tmp[k];
    }
    __syncthreads();
    #pragma unroll 2
    for (int a = 0; a < 128; ++a) {
      const floatx4 qx = *(const floatx4*)&lds[a * 68 + (tx << 2)];
      const floatx4 qy = *(const floatx4*)&lds[a * 68 + (ty << 2)];
      #pragma unroll
      for (int i = 0; i < 4; ++i)
        #pragma unroll
        for (int j = 0; j < 4; ++j) acc[i][j] += qx[i] * qy[j];
    }
  }
  float* o = Gpart + ((size_t)nh * 8 + chunk) * 4096;
  #pragma unroll
  for (int i = 0; i < 4; ++i)
    #pragma unroll
    for (int j = 0; j < 4; ++j) o[((tx << 2) + i) * 64 + (ty << 2) + j] = acc[i][j];
}

__global__ __launch_bounds__(256)
void k_gred(const float* __restrict__ Gpart, float* __restrict__ G) {
  int i = blockIdx.x * 256 + threadIdx.x;  // 64*4096
  int nh = i >> 12, e = i & 4095;
  const float* p = Gpart + (size_t)nh * 8 * 4096 + e;
  float s = 0.f;
  #pragma unroll
  for (int c = 0; c < 8; ++c) s += p[c * 4096];
  G[i] = s;
}

__global__ __launch_bounds__(256)
void k_qsum(const u16* __restrict__ QKV, float* __restrict__ qsum) {
  const int nh = blockIdx.x;
  const int n = nh >> 4, h = nh & 15;
  const int t = threadIdx.x, x = t & 63, g = t >> 6;
  const u16* base = QKV + (size_t)(n * 2048 + h * 128) * 3072;
  float s = 0.f;
  for (int a = g; a < 2048; a += 4)
    s += bf2f(base[(size_t)(a >> 4) * 3072 + ((a & 15) << 6) + x]);
  __shared__ float red[256];
  red[t] = s;
  __syncthreads();
  if (t < 64) qsum[nh * 64 + t] = red[t] + red[t + 64] + red[t + 128] + red[t + 192];
}

// ---------------- denom (Taylor) + diag: diag[b] = exp(s_bb)/(2048 + S1/1024 + S2/2/1024^2) ----
__global__ __launch_bounds__(128)
void k_denom(const u16* __restrict__ QKV, const float* __restrict__ G,
             const float* __restrict__ qsum, float* __restrict__ diag) {
  const int bx = blockIdx.x, nh = blockIdx.y;
  const int n = nh >> 4, h = nh & 15;
  const int t = threadIdx.x;
  __shared__ __align__(16) float Gs[4096];
  __shared__ float qs[64];
  for (int i = t; i < 4096; i += 128) Gs[i] = G[(size_t)nh * 4096 + i];
  if (t < 64) qs[t] = qsum[nh * 64 + t];
  __syncthreads();
  const int b = bx * 128 + t;
  const u16* rowb = QKV + (size_t)(n * 2048 + h * 128 + (b >> 4)) * 3072 + ((b & 15) << 6);
  const uint4* kp = (const uint4*)(rowb + 1024);   // K row (64 bf16)
  const uint4* qp = (const uint4*)(rowb);          // Q row
  float u[64];
  #pragma unroll
  for (int y = 0; y < 64; ++y) u[y] = 0.f;
  float s1 = 0.f, sbb = 0.f;
  for (int xo = 0; xo < 8; ++xo) {
    uint4 kv = kp[xo], qv = qp[xo];
    float kx[8], qx[8];
    unpack8(kv, kx); unpack8(qv, qx);
    #pragma unroll
    for (int xi = 0; xi < 8; ++xi) {
      const int x = xo * 8 + xi;
      s1  += qs[x] * kx[xi];
      sbb += qx[xi] * kx[xi];
      const floatx4* g4 = (const floatx4*)&Gs[x * 64];
      #pragma unroll
      for (int y4 = 0; y4 < 16; ++y4) {
        floatx4 g = g4[y4];
        u[y4 * 4 + 0] += kx[xi] * g[0];
        u[y4 * 4 + 1] += kx[xi] * g[1];
        u[y4 * 4 + 2] += kx[xi] * g[2];
        u[y4 * 4 + 3] += kx[xi] * g[3];
      }
    }
  }
  float quad = 0.f;
  #pragma unroll
  for (int yo = 0; yo < 8; ++yo) {
    uint4 kv = kp[yo];
    float ky[8]; unpack8(kv, ky);
    #pragma unroll
    for (int yi = 0; yi < 8; ++yi) quad += u[yo * 8 + yi] * ky[yi];
  }
  const float c1 = 0.0009765625f;  // 1/1024
  float denom = 2048.f + s1 * c1 + 0.5f * quad * c1 * c1;
  diag[(size_t)nh * 2048 + b] = expf(sbb * c1) / denom;
}

// ---------------- mid = diag * V (bf16) ----------------
__global__ __launch_bounds__(256)
void k_scalev(const u16* __restrict__ QKV, const float* __restrict__ diag, u16* __restrict__ mid) {
  size_t i = ((size_t)blockIdx.x * 256 + threadIdx.x) * 8;
  int R = (int)(i >> 10), c = (int)(i & 1023);
  int n = R >> 11, r = R & 2047;
  int h = r >> 7, a = ((r & 127) << 4) | (c >> 6);
  float d = diag[(size_t)((n << 4) | h) * 2048 + a];
  uint4 v = *(const uint4*)(QKV + (size_t)R * 3072 + 2048 + c);  // V at col offset 2048
  float f[8]; unpack8(v, f);
  union { u16 s[8]; uint4 v; } o;
  #pragma unroll
  for (int k = 0; k < 8; ++k) o.s[k] = f2bf(f[k] * d);
  *(uint4*)(mid + i) = o.v;
}

// ---------------- launch ----------------
extern "C" void kernel_launch(void* const* d_in, const int* in_sizes, int n_in,
                              void* d_out, int out_size, void* d_ws, size_t ws_size,
                              hipStream_t stream) {
  (void)in_sizes; (void)n_in; (void)out_size; (void)ws_size;
  const float* X  = (const float*)d_in[0];
  const float* Wq = (const float*)d_in[1];
  const float* bq = (const float*)d_in[2];
  const float* Wk = (const float*)d_in[3];
  const float* bk = (const float*)d_in[4];
  const float* Wv = (const float*)d_in[5];
  const float* bv = (const float*)d_in[6];
  const float* Wo = (const float*)d_in[7];
  const float* bo = (const float*)d_in[8];
  float* out = (float*)d_out;
  char* ws = (char*)d_ws;

  u16*   Xb    = (u16*)(ws + 0);                 // 16 MB
  u16*   Wqkvt = (u16*)(ws + 16777216);          //  6 MB (Wq^T|Wk^T|Wv^T)
  u16*   Wot   = (u16*)(ws + 23068672);          //  2 MB
  float* bias3 = (float*)(ws + 25165824);        // 12 KB
  u16*   QKV   = (u16*)(ws + 25182208);          // 48 MB (8192 x [Q|K|V])
  float* Gpart = (float*)(ws + 75513856);        //  8 MB
  float* G     = (float*)(ws + 83902464);        //  1 MB
  float* qsum  = (float*)(ws + 84951040);        // 16 KB
  float* diag  = (float*)(ws + 84967424);        // 512 KB
  u16*   mid   = (u16*)(ws + 85491712);          // 16 MB   (total ~97.5 MB)

  hipMemcpyAsync(bias3,        bq, 1024 * sizeof(float), hipMemcpyDeviceToDevice, stream);
  hipMemcpyAsync(bias3 + 1024, bk, 1024 * sizeof(float), hipMemcpyDeviceToDevice, stream);
  hipMemcpyAsync(bias3 + 2048, bv, 1024 * sizeof(float), hipMemcpyDeviceToDevice, stream);

  k_cvt_x<<<4096, 256, 0, stream>>>(X, Xb);
  k_wt<<<dim3(32, 32, 4), 256, 0, stream>>>(Wq, Wk, Wv, Wo, Wqkvt, Wot);
  k_gemm_bt<u16><<<dim3(24, 64), 256, 0, stream>>>(Xb, Wqkvt, bias3, QKV, 8192, 3072, 1024);
  k_gpart<<<dim3(8, 64), 256, 0, stream>>>(QKV, Gpart);
  k_gred<<<1024, 256, 0, stream>>>(Gpart, G);
  k_qsum<<<64, 256, 0, stream>>>(QKV, qsum);
  k_denom<<<dim3(16, 64), 128, 0, stream>>>(QKV, G, qsum, diag);
  k_scalev<<<4096, 256, 0, stream>>>(QKV, diag, mid);
  k_gemm_bt<float><<<dim3(8, 64), 256, 0, stream>>>(mid, Wot, bo, out, 8192, 1024, 1024);
}

// Round 2
// 268.770 us; speedup vs baseline: 1.4824x; 1.4824x over previous
//
#include <hip/hip_runtime.h>
#include <type_traits>

typedef unsigned short u16;
typedef __attribute__((ext_vector_type(8))) short short8;   // 8 bf16 (4 VGPRs) MFMA frag
typedef __attribute__((ext_vector_type(4))) float floatx4;  // MFMA acc

#define DEV __device__ __forceinline__

DEV float bf2f(u16 u) { return __uint_as_float(((unsigned)u) << 16); }
DEV u16 f2bf(float f) {                       // RNE fp32->bf16
  unsigned u = __float_as_uint(f);
  u += 0x7fffu + ((u >> 16) & 1u);
  return (u16)(u >> 16);
}
DEV void unpack8(uint4 v, float* f) {
  f[0] = __uint_as_float(v.x << 16); f[1] = __uint_as_float(v.x & 0xffff0000u);
  f[2] = __uint_as_float(v.y << 16); f[3] = __uint_as_float(v.y & 0xffff0000u);
  f[4] = __uint_as_float(v.z << 16); f[5] = __uint_as_float(v.z & 0xffff0000u);
  f[6] = __uint_as_float(v.w << 16); f[7] = __uint_as_float(v.w & 0xffff0000u);
}
DEV void async16(const void* g, void* lds) {  // 16B global->LDS DMA (lane*16 implicit)
  __builtin_amdgcn_global_load_lds((const __attribute__((address_space(1))) void*)g,
                                   (__attribute__((address_space(3))) void*)lds, 16, 0, 0);
}

// ---------------- elementwise converts ----------------
__global__ __launch_bounds__(256) void k_cvt_x(const float* __restrict__ X, u16* __restrict__ Xb) {
  size_t i = ((size_t)blockIdx.x * 256 + threadIdx.x) * 8;
  float4 a = *(const float4*)(X + i);
  float4 b = *(const float4*)(X + i + 4);
  union { u16 s[8]; uint4 v; } o;
  o.s[0]=f2bf(a.x); o.s[1]=f2bf(a.y); o.s[2]=f2bf(a.z); o.s[3]=f2bf(a.w);
  o.s[4]=f2bf(b.x); o.s[5]=f2bf(b.y); o.s[6]=f2bf(b.z); o.s[7]=f2bf(b.w);
  *(uint4*)(Xb + i) = o.v;
}

// transpose-convert 1024x1024 fp32 (KxN) -> bf16 (NxK); z selects matrix
__global__ __launch_bounds__(256) void k_wt(const float* __restrict__ Wq, const float* __restrict__ Wk,
                                            const float* __restrict__ Wv, const float* __restrict__ Wo,
                                            u16* __restrict__ Wqkvt, u16* __restrict__ Wot) {
  const float* src; u16* dst;
  switch (blockIdx.z) {
    case 0:  src = Wq; dst = Wqkvt;            break;
    case 1:  src = Wk; dst = Wqkvt + 1048576;  break;
    case 2:  src = Wv; dst = Wqkvt + 2097152;  break;
    default: src = Wo; dst = Wot;              break;
  }
  __shared__ float tile[32][33];
  int tx = threadIdx.x & 31, ty = threadIdx.x >> 5;  // 32 x 8
  int n0 = blockIdx.x * 32, k0 = blockIdx.y * 32;
  #pragma unroll
  for (int i = 0; i < 32; i += 8) tile[ty + i][tx] = src[(size_t)(k0 + ty + i) * 1024 + n0 + tx];
  __syncthreads();
  #pragma unroll
  for (int i = 0; i < 32; i += 8) dst[(size_t)(n0 + ty + i) * 1024 + k0 + tx] = f2bf(tile[tx][ty + i]);
}

// ---------------- bf16 MFMA GEMM: C[M,N] = A[M,K] * Bt[N,K]^T + bias ----------------
// m97 structure: 128x128 tile, BK=32, 4 waves each 64x64 (4x4 MFMA 16x16x32), global_load_lds w=16
template <typename OutT>
__global__ __launch_bounds__(256)
void k_gemm_bt(const u16* __restrict__ A, const u16* __restrict__ B,
               const float* __restrict__ bias, OutT* __restrict__ C,
               int M, int N, int K) {
  __shared__ __align__(16) u16 As[128 * 32];
  __shared__ __align__(16) u16 Bs[128 * 32];
  const int t = threadIdx.x;
  const int w = t >> 6, lane = t & 63;
  const int m0 = blockIdx.y << 7, n0 = blockIdx.x << 7;
  const int wr = (w >> 1) << 6, wc = (w & 1) << 6;

  floatx4 acc[4][4];
  #pragma unroll
  for (int i = 0; i < 4; ++i)
    #pragma unroll
    for (int j = 0; j < 4; ++j)
      #pragma unroll
      for (int k = 0; k < 4; ++k) acc[i][j][k] = 0.f;

  const int rowA0 = t >> 2, koff = (t & 3) << 3;      // round 0: idx = t
  const int rowA1 = (256 + t) >> 2;                   // round 1: idx = 256+t (same koff)
  const int lr = lane & 15, lko = (lane >> 4) << 3;

  for (int kt = 0; kt < K; kt += 32) {
    __syncthreads();
    async16(A + (size_t)(m0 + rowA0) * K + kt + koff, &As[(w << 6) * 8]);
    async16(B + (size_t)(n0 + rowA0) * K + kt + koff, &Bs[(w << 6) * 8]);
    async16(A + (size_t)(m0 + rowA1) * K + kt + koff, &As[(256 + (w << 6)) * 8]);
    async16(B + (size_t)(n0 + rowA1) * K + kt + koff, &Bs[(256 + (w << 6)) * 8]);
    __syncthreads();
    short8 af[4], bfr[4];
    #pragma unroll
    for (int i = 0; i < 4; ++i) af[i]  = *(const short8*)&As[(wr + (i << 4) + lr) * 32 + lko];
    #pragma unroll
    for (int j = 0; j < 4; ++j) bfr[j] = *(const short8*)&Bs[(wc + (j << 4) + lr) * 32 + lko];
    #pragma unroll
    for (int i = 0; i < 4; ++i)
      #pragma unroll
      for (int j = 0; j < 4; ++j)
        acc[i][j] = __builtin_amdgcn_mfma_f32_16x16x32_bf16(af[i], bfr[j], acc[i][j], 0, 0, 0);
  }
  // C/D layout: col = lane&15, row = (lane>>4)*4 + reg
  const int lq = (lane >> 4) << 2;
  #pragma unroll
  for (int j = 0; j < 4; ++j) {
    const int cn = n0 + wc + (j << 4) + lr;
    const float bv = bias[cn];
    #pragma unroll
    for (int i = 0; i < 4; ++i) {
      const int rm = m0 + wr + (i << 4) + lq;
      #pragma unroll
      for (int rr = 0; rr < 4; ++rr) {
        float v = acc[i][j][rr] + bv;
        if constexpr (std::is_same<OutT, u16>::value) C[(size_t)(rm + rr) * N + cn] = f2bf(v);
        else                                          C[(size_t)(rm + rr) * N + cn] = v;
      }
    }
  }
}

// ---------------- Gram partials: Gpart[nh][chunk] = sum over 256 a of q_x q_y ----------------
__global__ __launch_bounds__(256)
void k_gpart(const u16* __restrict__ QKV, float* __restrict__ Gpart) {
  const int chunk = blockIdx.x;            // 0..7  (256 a each)
  const int nh = blockIdx.y;               // 0..63
  const int n = nh >> 4, h = nh & 15;
  const int t = threadIdx.x;
  __shared__ __align__(16) float lds[128 * 68];
  const u16* Qb = QKV + (size_t)(n * 2048 + h * 128 + chunk * 16) * 3072;  // Q at col offset 0
  float acc[4][4];
  #pragma unroll
  for (int i = 0; i < 4; ++i)
    #pragma unroll
    for (int j = 0; j < 4; ++j) acc[i][j] = 0.f;
  const int tx = t & 15, ty = t >> 4;
  for (int s = 0; s < 2; ++s) {            // two 128-a stages (8 Q rows each)
    __syncthreads();
    #pragma unroll
    for (int i = 0; i < 4; ++i) {
      int f = ((i << 8) + t) << 3;         // 0..8191
      int row = f >> 10, j = f & 1023;
      uint4 v = *(const uint4*)(Qb + (size_t)((s << 3) + row) * 3072 + j);
      float tmp[8]; unpack8(v, tmp);
      float* d = &lds[((row << 4) + (j >> 6)) * 68 + (j & 63)];
      #pragma unroll
      for (int k = 0; k < 8; ++k) d[k] = tmp[k];
    }
    __syncthreads();
    #pragma unroll 2
    for (int a = 0; a < 128; ++a) {
      const floatx4 qx = *(const floatx4*)&lds[a * 68 + (tx << 2)];
      const floatx4 qy = *(const floatx4*)&lds[a * 68 + (ty << 2)];
      #pragma unroll
      for (int i = 0; i < 4; ++i)
        #pragma unroll
        for (int j = 0; j < 4; ++j) acc[i][j] += qx[i] * qy[j];
    }
  }
  float* o = Gpart + ((size_t)nh * 8 + chunk) * 4096;
  #pragma unroll
  for (int i = 0; i < 4; ++i)
    #pragma unroll
    for (int j = 0; j < 4; ++j) o[((tx << 2) + i) * 64 + (ty << 2) + j] = acc[i][j];
}

__global__ __launch_bounds__(256)
void k_gred(const float* __restrict__ Gpart, float* __restrict__ G) {
  int i = blockIdx.x * 256 + threadIdx.x;  // 64*4096
  int nh = i >> 12, e = i & 4095;
  const float* p = Gpart + (size_t)nh * 8 * 4096 + e;
  float s = 0.f;
  #pragma unroll
  for (int c = 0; c < 8; ++c) s += p[c * 4096];
  G[i] = s;
}

// ---------------- qsum partials: qpart[nh][rc][x] = col-sum (mod 64) of a 16-row Q slab ------
// Parallel rewrite: 512 blocks, uint4 coalesced loads, fixed x-phase per thread, LDS reduce.
__global__ __launch_bounds__(256)
void k_qsum(const u16* __restrict__ QKV, float* __restrict__ qpart) {
  const int nh = blockIdx.x;               // 0..63
  const int rc = blockIdx.y;               // 0..7  (16 rows each)
  const int n = nh >> 4, h = nh & 15;
  const int t = threadIdx.x;
  const u16* base = QKV + (size_t)(n * 2048 + h * 128 + rc * 16) * 3072;  // Q cols 0..1023
  const int row_off = t >> 7;              // 0..1
  const int col = (t & 127) << 3;          // 0..1016 step 8
  float acc[8];
  #pragma unroll
  for (int k = 0; k < 8; ++k) acc[k] = 0.f;
  #pragma unroll
  for (int it = 0; it < 8; ++it) {         // 16 rows, 2 per iteration
    uint4 v = *(const uint4*)(base + (size_t)(it * 2 + row_off) * 3072 + col);
    float f[8]; unpack8(v, f);
    #pragma unroll
    for (int k = 0; k < 8; ++k) acc[k] += f[k];
  }
  // acc[k] contributes to x = (t&7)*8 + k
  __shared__ float red[256][8];            // 8 KB
  #pragma unroll
  for (int k = 0; k < 8; ++k) red[t][k] = acc[k];
  __syncthreads();
  if (t < 64) {
    const int g = t >> 3, k = t & 7;       // x = t
    float s = 0.f;
    #pragma unroll
    for (int i = 0; i < 32; ++i) s += red[g + 8 * i][k];
    qpart[((size_t)nh * 8 + rc) * 64 + t] = s;
  }
}

// ---------------- denom (Taylor) + diag: diag[b] = exp(s_bb)/(2048 + S1/1024 + S2/2/1024^2) ----
__global__ __launch_bounds__(128)
void k_denom(const u16* __restrict__ QKV, const float* __restrict__ G,
             const float* __restrict__ qpart, float* __restrict__ diag) {
  const int bx = blockIdx.x, nh = blockIdx.y;
  const int n = nh >> 4, h = nh & 15;
  const int t = threadIdx.x;
  __shared__ __align__(16) float Gs[4096];
  __shared__ float qs[64];
  for (int i = t; i < 4096; i += 128) Gs[i] = G[(size_t)nh * 4096 + i];
  if (t < 64) {
    float s = 0.f;
    #pragma unroll
    for (int rc = 0; rc < 8; ++rc) s += qpart[((size_t)nh * 8 + rc) * 64 + t];
    qs[t] = s;
  }
  __syncthreads();
  const int b = bx * 128 + t;
  const u16* rowb = QKV + (size_t)(n * 2048 + h * 128 + (b >> 4)) * 3072 + ((b & 15) << 6);
  const uint4* kp = (const uint4*)(rowb + 1024);   // K row (64 bf16)
  const uint4* qp = (const uint4*)(rowb);          // Q row
  float u[64];
  #pragma unroll
  for (int y = 0; y < 64; ++y) u[y] = 0.f;
  float s1 = 0.f, sbb = 0.f;
  for (int xo = 0; xo < 8; ++xo) {
    uint4 kv = kp[xo], qv = qp[xo];
    float kx[8], qx[8];
    unpack8(kv, kx); unpack8(qv, qx);
    #pragma unroll
    for (int xi = 0; xi < 8; ++xi) {
      const int x = xo * 8 + xi;
      s1  += qs[x] * kx[xi];
      sbb += qx[xi] * kx[xi];
      const floatx4* g4 = (const floatx4*)&Gs[x * 64];
      #pragma unroll
      for (int y4 = 0; y4 < 16; ++y4) {
        floatx4 g = g4[y4];
        u[y4 * 4 + 0] += kx[xi] * g[0];
        u[y4 * 4 + 1] += kx[xi] * g[1];
        u[y4 * 4 + 2] += kx[xi] * g[2];
        u[y4 * 4 + 3] += kx[xi] * g[3];
      }
    }
  }
  float quad = 0.f;
  #pragma unroll
  for (int yo = 0; yo < 8; ++yo) {
    uint4 kv = kp[yo];
    float ky[8]; unpack8(kv, ky);
    #pragma unroll
    for (int yi = 0; yi < 8; ++yi) quad += u[yo * 8 + yi] * ky[yi];
  }
  const float c1 = 0.0009765625f;  // 1/1024
  float denom = 2048.f + s1 * c1 + 0.5f * quad * c1 * c1;
  diag[(size_t)nh * 2048 + b] = expf(sbb * c1) / denom;
}

// ---------------- mid = diag * V (bf16) ----------------
__global__ __launch_bounds__(256)
void k_scalev(const u16* __restrict__ QKV, const float* __restrict__ diag, u16* __restrict__ mid) {
  size_t i = ((size_t)blockIdx.x * 256 + threadIdx.x) * 8;
  int R = (int)(i >> 10), c = (int)(i & 1023);
  int n = R >> 11, r = R & 2047;
  int h = r >> 7, a = ((r & 127) << 4) | (c >> 6);
  float d = diag[(size_t)((n << 4) | h) * 2048 + a];
  uint4 v = *(const uint4*)(QKV + (size_t)R * 3072 + 2048 + c);  // V at col offset 2048
  float f[8]; unpack8(v, f);
  union { u16 s[8]; uint4 v; } o;
  #pragma unroll
  for (int k = 0; k < 8; ++k) o.s[k] = f2bf(f[k] * d);
  *(uint4*)(mid + i) = o.v;
}

// ---------------- launch ----------------
extern "C" void kernel_launch(void* const* d_in, const int* in_sizes, int n_in,
                              void* d_out, int out_size, void* d_ws, size_t ws_size,
                              hipStream_t stream) {
  (void)in_sizes; (void)n_in; (void)out_size; (void)ws_size;
  const float* X  = (const float*)d_in[0];
  const float* Wq = (const float*)d_in[1];
  const float* bq = (const float*)d_in[2];
  const float* Wk = (const float*)d_in[3];
  const float* bk = (const float*)d_in[4];
  const float* Wv = (const float*)d_in[5];
  const float* bv = (const float*)d_in[6];
  const float* Wo = (const float*)d_in[7];
  const float* bo = (const float*)d_in[8];
  float* out = (float*)d_out;
  char* ws = (char*)d_ws;

  u16*   Xb    = (u16*)(ws + 0);                 // 16 MB
  u16*   Wqkvt = (u16*)(ws + 16777216);          //  6 MB (Wq^T|Wk^T|Wv^T)
  u16*   Wot   = (u16*)(ws + 23068672);          //  2 MB
  float* bias3 = (float*)(ws + 25165824);        // 12 KB
  u16*   QKV   = (u16*)(ws + 25182208);          // 48 MB (8192 x [Q|K|V])
  float* Gpart = (float*)(ws + 75513856);        //  8 MB (dead after k_gred)
  float* G     = (float*)(ws + 83902464);        //  1 MB
  float* qpart = (float*)(ws + 84951040);        // 128 KB (64*8*64 f32)
  float* diag  = (float*)(ws + 85491712);        // 512 KB
  u16*   mid   = (u16*)(ws + 86016000);          // 16 MB

  hipMemcpyAsync(bias3,        bq, 1024 * sizeof(float), hipMemcpyDeviceToDevice, stream);
  hipMemcpyAsync(bias3 + 1024, bk, 1024 * sizeof(float), hipMemcpyDeviceToDevice, stream);
  hipMemcpyAsync(bias3 + 2048, bv, 1024 * sizeof(float), hipMemcpyDeviceToDevice, stream);

  k_cvt_x<<<4096, 256, 0, stream>>>(X, Xb);
  k_wt<<<dim3(32, 32, 4), 256, 0, stream>>>(Wq, Wk, Wv, Wo, Wqkvt, Wot);
  k_gemm_bt<u16><<<dim3(24, 64), 256, 0, stream>>>(Xb, Wqkvt, bias3, QKV, 8192, 3072, 1024);
  k_gpart<<<dim3(8, 64), 256, 0, stream>>>(QKV, Gpart);
  k_gred<<<1024, 256, 0, stream>>>(Gpart, G);
  k_qsum<<<dim3(64, 8), 256, 0, stream>>>(QKV, qpart);
  k_denom<<<dim3(16, 64), 128, 0, stream>>>(QKV, G, qpart, diag);
  k_scalev<<<4096, 256, 0, stream>>>(QKV, diag, mid);
  k_gemm_bt<float><<<dim3(8, 64), 256, 0, stream>>>(mid, Wot, bo, out, 8192, 1024, 1024);
}